// Round 2
// baseline (541.950 us; speedup 1.0000x reference)
//
#include <hip/hip_runtime.h>
#include <hip/hip_bf16.h>
#include <math.h>

#define SEQ 2048
#define DM 2048
#define NH 16
#define HD 128
#define QKV_N 6144

typedef __bf16 bf16;
typedef __bf16 bf16x8 __attribute__((ext_vector_type(8)));
typedef __bf16 bf16x4v __attribute__((ext_vector_type(4)));
typedef __bf16 bf16x2v __attribute__((ext_vector_type(2)));
typedef float f32x4 __attribute__((ext_vector_type(4)));

__device__ inline void async16(const void* g, void* l) {
    __builtin_amdgcn_global_load_lds((const __attribute__((address_space(1))) void*)g,
                                     (__attribute__((address_space(3))) void*)l, 16, 0, 0);
}

// ---- x fp32 -> bf16 -------------------------------------------------------
__global__ void k_convert_x(const float* __restrict__ x, bf16* __restrict__ xb) {
    int i = blockIdx.x * 256 + threadIdx.x;           // 1M float4s
    float4 v = ((const float4*)x)[i];
    bf16x4v o;
    o.x = (bf16)v.x; o.y = (bf16)v.y; o.z = (bf16)v.z; o.w = (bf16)v.w;
    ((bf16x4v*)xb)[i] = o;
}

// ---- weight transpose+convert: dst[n*2048+k] = (bf16)src[k*2048+n] --------
__global__ void k_transpose_w(const float* __restrict__ src, bf16* __restrict__ dst) {
    __shared__ float tile[32][33];
    int tx = threadIdx.x, ty = threadIdx.y;
    int bx = blockIdx.x * 32, by = blockIdx.y * 32;
    tile[ty][tx] = src[(size_t)(by + ty) * DM + bx + tx];
    __syncthreads();
    dst[(size_t)(bx + ty) * DM + by + tx] = (bf16)tile[tx][ty];
}

// ---- V transpose: vT[c*2048+s] = qkv[s*6144+4096+c], c in [0,2048) --------
__global__ void k_transpose_v(const bf16* __restrict__ qkv, bf16* __restrict__ vT) {
    __shared__ bf16 tile[32][33];
    int tx = threadIdx.x, ty = threadIdx.y;
    int bx = blockIdx.x * 32, by = blockIdx.y * 32;   // bx: channel, by: seq
    tile[ty][tx] = qkv[(size_t)(by + ty) * QKV_N + 2 * DM + bx + tx];
    __syncthreads();
    vT[(size_t)(bx + ty) * SEQ + by + tx] = tile[tx][ty];
}

// ---- RoPE in-place on Q and K (HD=128 -> 64 (re,im) pairs per head) -------
__global__ void k_rotary(bf16* __restrict__ qkv, const float* __restrict__ cosT,
                         const float* __restrict__ sinT) {
    int idx = blockIdx.x * 256 + threadIdx.x;         // SEQ*NH*64 = 2M threads
    int i = idx & 63;                                 // pair index in [0,64)
    int h = (idx >> 6) & 15;
    int s = idx >> 10;
    float c = cosT[s * 64 + i], sn = sinT[s * 64 + i];
    size_t base = (size_t)s * QKV_N + h * HD + 2 * i;
    bf16x2v q = *(bf16x2v*)&qkv[base];
    float qr = (float)q.x, qi = (float)q.y;
    bf16x2v qo;
    qo.x = (bf16)(qr * c - qi * sn);
    qo.y = (bf16)(qr * sn + qi * c);
    *(bf16x2v*)&qkv[base] = qo;
    bf16x2v k = *(bf16x2v*)&qkv[base + DM];
    float kr = (float)k.x, ki = (float)k.y;
    bf16x2v ko;
    ko.x = (bf16)(kr * c - ki * sn);
    ko.y = (bf16)(kr * sn + ki * c);
    *(bf16x2v*)&qkv[base + DM] = ko;
}

// ---- C[M][N] = A[M][K] * Bt[N][K]^T, bf16 in, OutT out --------------------
// 128x128 tile, BK=32, 256 threads (2x2 waves, each 64x64 via 4x4 16x16x32 MFMA)
template <typename OutT>
__global__ __launch_bounds__(256) void k_gemm_bt(const bf16* __restrict__ A,
                                                 const bf16* __restrict__ Bt,
                                                 OutT* __restrict__ C,
                                                 int M, int N, int K) {
    __shared__ bf16 As[128 * 32];
    __shared__ bf16 Bs[128 * 32];
    const int t = threadIdx.x;
    const int lane = t & 63;
    const int w = t >> 6;
    const int wr = (w >> 1) * 64, wc = (w & 1) * 64;
    const int l15 = lane & 15, quad = lane >> 4;
    const size_t bm = (size_t)blockIdx.y * 128, bn = (size_t)blockIdx.x * 128;
    f32x4 acc[4][4];
#pragma unroll
    for (int i = 0; i < 4; ++i)
#pragma unroll
        for (int j = 0; j < 4; ++j) acc[i][j] = (f32x4){0.f, 0.f, 0.f, 0.f};

    const int c0 = t, c1 = t + 256;                 // 512 16B-chunks per tile
    const int row0 = c0 >> 2, k80 = (c0 & 3) * 8;
    const int row1 = c1 >> 2, k81 = (c1 & 3) * 8;

    for (int kt = 0; kt < K; kt += 32) {
        async16(&A[(bm + row0) * K + kt + k80], &As[c0 * 8]);
        async16(&A[(bm + row1) * K + kt + k81], &As[c1 * 8]);
        async16(&Bt[(bn + row0) * K + kt + k80], &Bs[c0 * 8]);
        async16(&Bt[(bn + row1) * K + kt + k81], &Bs[c1 * 8]);
        __syncthreads();
        bf16x8 af[4], bfm[4];
#pragma unroll
        for (int mi = 0; mi < 4; ++mi)
            af[mi] = *(const bf16x8*)&As[(wr + mi * 16 + l15) * 32 + quad * 8];
#pragma unroll
        for (int ni = 0; ni < 4; ++ni)
            bfm[ni] = *(const bf16x8*)&Bs[(wc + ni * 16 + l15) * 32 + quad * 8];
#pragma unroll
        for (int mi = 0; mi < 4; ++mi)
#pragma unroll
            for (int ni = 0; ni < 4; ++ni)
                acc[mi][ni] = __builtin_amdgcn_mfma_f32_16x16x32_bf16(
                    af[mi], bfm[ni], acc[mi][ni], 0, 0, 0);
        __syncthreads();
    }
#pragma unroll
    for (int mi = 0; mi < 4; ++mi)
#pragma unroll
        for (int ni = 0; ni < 4; ++ni)
#pragma unroll
            for (int r = 0; r < 4; ++r) {
                size_t row = bm + wr + mi * 16 + quad * 4 + r;
                size_t col = bn + wc + ni * 16 + l15;
                C[row * (size_t)N + col] = (OutT)acc[mi][ni][r];
            }
}

// ---- causal flash attention, HD=128 --------------------------------------
// grid (32 qblocks, 16 heads), 256 threads = 4 waves; wave w owns 16 q-rows.
__global__ __launch_bounds__(256) void k_flash(const bf16* __restrict__ qkv,
                                               const bf16* __restrict__ vT,
                                               bf16* __restrict__ out) {
    __shared__ bf16 Pl[4][16][32];
    const int t = threadIdx.x;
    const int lane = t & 63;
    const int w = t >> 6;
    const int l15 = lane & 15, quad = lane >> 4;
    const int h = blockIdx.y;
    const int qb = blockIdx.x;
    const int q0 = qb * 64 + w * 16;
    const float scale = 0.08838834764831845f;        // 1/sqrt(128)

    const size_t qrow = (size_t)(q0 + l15) * QKV_N + h * HD;
    bf16x8 aq[4];
#pragma unroll
    for (int u = 0; u < 4; ++u)
        aq[u] = *(const bf16x8*)&qkv[qrow + u * 32 + quad * 8];

    f32x4 o[8];
#pragma unroll
    for (int c = 0; c < 8; ++c) o[c] = (f32x4){0.f, 0.f, 0.f, 0.f};
    float m_r[4] = {-1e30f, -1e30f, -1e30f, -1e30f};
    float l_r[4] = {0.f, 0.f, 0.f, 0.f};

    const int nkt = 2 * qb + 2;                      // 32-key tiles (causal)
    for (int kt = 0; kt < nkt; ++kt) {
        const int kbase = kt * 32;
        f32x4 s[2];
#pragma unroll
        for (int sub = 0; sub < 2; ++sub) {
            size_t kr = (size_t)(kbase + sub * 16 + l15) * QKV_N + DM + h * HD;
            f32x4 z = (f32x4){0.f, 0.f, 0.f, 0.f};
#pragma unroll
            for (int u = 0; u < 4; ++u) {
                bf16x8 kb = *(const bf16x8*)&qkv[kr + u * 32 + quad * 8];
                z = __builtin_amdgcn_mfma_f32_16x16x32_bf16(aq[u], kb, z, 0, 0, 0);
            }
            s[sub] = z;
        }
        float alpha[4];
#pragma unroll
        for (int r = 0; r < 4; ++r) {
            int qr = q0 + quad * 4 + r;
            float s0 = (kbase + l15 <= qr) ? s[0][r] * scale : -1e30f;
            float s1 = (kbase + 16 + l15 <= qr) ? s[1][r] * scale : -1e30f;
            float tm = fmaxf(s0, s1);
            tm = fmaxf(tm, __shfl_xor(tm, 1, 16));
            tm = fmaxf(tm, __shfl_xor(tm, 2, 16));
            tm = fmaxf(tm, __shfl_xor(tm, 4, 16));
            tm = fmaxf(tm, __shfl_xor(tm, 8, 16));
            float nm = fmaxf(m_r[r], tm);
            float al = __expf(m_r[r] - nm);
            float p0 = __expf(s0 - nm);
            float p1 = __expf(s1 - nm);
            float rs = p0 + p1;
            rs += __shfl_xor(rs, 1, 16);
            rs += __shfl_xor(rs, 2, 16);
            rs += __shfl_xor(rs, 4, 16);
            rs += __shfl_xor(rs, 8, 16);
            l_r[r] = l_r[r] * al + rs;
            m_r[r] = nm;
            alpha[r] = al;
            Pl[w][quad * 4 + r][l15] = (bf16)p0;
            Pl[w][quad * 4 + r][16 + l15] = (bf16)p1;
        }
#pragma unroll
        for (int c = 0; c < 8; ++c)
#pragma unroll
            for (int r = 0; r < 4; ++r) o[c][r] *= alpha[r];
        // P: C-layout -> A-layout via wave-private LDS round trip
        bf16x8 pf = *(const bf16x8*)&Pl[w][l15][quad * 8];
#pragma unroll
        for (int c = 0; c < 8; ++c) {
            bf16x8 vb = *(const bf16x8*)&vT[(size_t)(h * HD + c * 16 + l15) * SEQ +
                                            kbase + quad * 8];
            o[c] = __builtin_amdgcn_mfma_f32_16x16x32_bf16(pf, vb, o[c], 0, 0, 0);
        }
    }
#pragma unroll
    for (int c = 0; c < 8; ++c)
#pragma unroll
        for (int r = 0; r < 4; ++r)
            out[(size_t)(q0 + quad * 4 + r) * DM + h * HD + c * 16 + l15] =
                (bf16)(o[c][r] / l_r[r]);
}

extern "C" void kernel_launch(void* const* d_in, const int* in_sizes, int n_in,
                              void* d_out, int out_size, void* d_ws, size_t ws_size,
                              hipStream_t stream) {
    const float* x  = (const float*)d_in[0];
    const float* fc = (const float*)d_in[1];
    const float* fs = (const float*)d_in[2];
    // d_in[3] = mask (unused; causal mask applied analytically)
    const float* wq = (const float*)d_in[4];
    const float* wk = (const float*)d_in[5];
    const float* wv = (const float*)d_in[6];
    const float* wo = (const float*)d_in[7];
    float* out = (float*)d_out;

    char* ws = (char*)d_ws;
    bf16* xb  = (bf16*)(ws);                          //  8MB, reused as attn_out
    bf16* wT  = (bf16*)(ws + (size_t)(8u  << 20));    // 24MB  (wq|wk|wv transposed)
    bf16* woT = (bf16*)(ws + (size_t)(32u << 20));    //  8MB
    bf16* qkv = (bf16*)(ws + (size_t)(40u << 20));    // 24MB  [seq][6144]
    bf16* vT  = (bf16*)(ws + (size_t)(64u << 20));    //  8MB  [c][seq]

    dim3 tb(32, 32), tg(64, 64);
    k_convert_x<<<4096, 256, 0, stream>>>(x, xb);
    k_transpose_w<<<tg, tb, 0, stream>>>(wq, wT);
    k_transpose_w<<<tg, tb, 0, stream>>>(wk, wT + (size_t)DM * DM);
    k_transpose_w<<<tg, tb, 0, stream>>>(wv, wT + (size_t)2 * DM * DM);
    k_transpose_w<<<tg, tb, 0, stream>>>(wo, woT);
    k_gemm_bt<bf16><<<dim3(48, 16), 256, 0, stream>>>(xb, wT, qkv, SEQ, QKV_N, DM);
    k_rotary<<<8192, 256, 0, stream>>>(qkv, fc, fs);
    k_transpose_v<<<tg, tb, 0, stream>>>(qkv, vT);
    k_flash<<<dim3(32, 16), 256, 0, stream>>>(qkv, vT, xb);
    k_gemm_bt<float><<<dim3(16, 16), 256, 0, stream>>>(xb, woT, out, SEQ, DM, DM);
}